// Round 6
// baseline (1388.802 us; speedup 1.0000x reference)
//
#include <hip/hip_runtime.h>
#include <math.h>

#define NPTS 65536
#define BATCH 32

// =====================================================================
// transpose x (B,N,2) -> x_t (N, 64)  [x_t[n][b*2+c] = x[b][n][c]]
// =====================================================================
__global__ __launch_bounds__(256) void transpose_kernel(const float* __restrict__ x,
                                                        float* __restrict__ xt)
{
    __shared__ float tile[64][65];
    int n0 = blockIdx.x * 64;
    int tid = threadIdx.x;
    int lane = tid & 63, w = tid >> 6;
    const float2* x2 = (const float2*)x;
#pragma unroll
    for (int bq = 0; bq < 8; ++bq) {
        int b = bq * 4 + w;
        float2 v = x2[(size_t)b * NPTS + n0 + lane];
        tile[lane][b * 2 + 0] = v.x;
        tile[lane][b * 2 + 1] = v.y;
    }
    __syncthreads();
    int f4 = tid & 15;
#pragma unroll
    for (int rq = 0; rq < 4; ++rq) {
        int r = rq * 16 + (tid >> 4);
        float4 v = make_float4(tile[r][f4 * 4 + 0], tile[r][f4 * 4 + 1],
                               tile[r][f4 * 4 + 2], tile[r][f4 * 4 + 3]);
        *(float4*)&xt[(size_t)(n0 + r) * 64 + f4 * 4] = v;
    }
}

// =====================================================================
// smooth (one SFC): s[(b*2+c)*N + n] = tanh(sum_k xt[ord[clip(n-1+k)]][b*2+c]*sp_w[n,k]+sp_b[n])
// Row-gather from x_t staged in LDS (float4 loads, conflict-free layout).
// =====================================================================
__global__ __launch_bounds__(256) void smooth_kernel(const float* __restrict__ xt,
                                                     const int* __restrict__ ord,
                                                     const float* __restrict__ sp_w,
                                                     const float* __restrict__ sp_b,
                                                     float* __restrict__ s)
{
    __shared__ int s_idx[130];
    __shared__ float rows[130][65];
    int n0 = blockIdx.x * 128;
    int tid = threadIdx.x;
    if (tid < 130) {
        int g = n0 - 1 + tid;
        g = g < 0 ? 0 : (g > NPTS - 1 ? NPTS - 1 : g);
        s_idx[tid] = ord[g];
    }
    __syncthreads();
    for (int q = tid; q < 130 * 16; q += 256) {
        int r = q >> 4, f4 = q & 15;
        float4 v = *(const float4*)&xt[(size_t)s_idx[r] * 64 + f4 * 4];
        rows[r][f4 * 4 + 0] = v.x; rows[r][f4 * 4 + 1] = v.y;
        rows[r][f4 * 4 + 2] = v.z; rows[r][f4 * 4 + 3] = v.w;
    }
    __syncthreads();
    int n_local = tid & 127, half = tid >> 7;
    int n = n0 + n_local;
    float w0 = sp_w[n * 3 + 0], w1 = sp_w[n * 3 + 1], w2 = sp_w[n * 3 + 2];
    float bb = sp_b[n];
#pragma unroll 4
    for (int bc = 0; bc < 64; bc += 2) {
        int bce = bc + half;
        float v = w0 * rows[n_local][bce] + w1 * rows[n_local + 1][bce]
                + w2 * rows[n_local + 2][bce] + bb;
        s[(size_t)bce * NPTS + n] = tanhf(v);
    }
}

// =====================================================================
// Direct strided conv1d + bias + tanh. No input staging: each thread does
// independent aligned float4 global loads (MLP hides latency). Weights in LDS
// (wave-uniform broadcast). LPT adjacent outputs share the sliding window
// (window shifts exactly 1 float4 per output since S=4).
// Rows padded: ISTR/OSTR multiples of 4 floats -> all float4 loads 16B-aligned.
// =====================================================================
template <int CIN, int COUT, int CPT, int LPB, int LPT, int ISTR, int OSTR,
          int LIN, int LOUT, bool CONCAT>
__global__ __launch_bounds__(256, 2) void conv_direct(
    const float* __restrict__ in,      // (B, CIN, ISTR)
    const float* __restrict__ w,       // (COUT, CIN, 32)
    const float* __restrict__ bias,    // (COUT,)
    float* __restrict__ out)
{
    constexpr int G = COUT / CPT;          // channel groups; G*LPB == 256
    constexpr int SPANL = LPB * LPT;       // output positions per block
    constexpr int NT = (LOUT + SPANL - 1) / SPANL;
    constexpr int NV = 8 + LPT - 1;        // float4s in sliding window

    __shared__ float w_s[COUT * CIN * 32];

    int bid = blockIdx.x;
    int tile = bid % NT;
    int b = bid / NT;
    int tid = threadIdx.x;

    for (int idx = tid; idx < COUT * CIN * 32; idx += 256)
        w_s[idx] = w[idx];
    __syncthreads();

    int lpos = tid % LPB;
    int cog = tid / LPB;
    int l0 = tile * SPANL + lpos * LPT;
    int co0 = cog * CPT;

    float acc[CPT][LPT];
#pragma unroll
    for (int c = 0; c < CPT; ++c) {
        float bv = bias[co0 + c];
#pragma unroll
        for (int j = 0; j < LPT; ++j) acc[c][j] = bv;
    }

    const float* inb = in + (size_t)b * CIN * ISTR;
    int base = 4 * l0 - 16;
    bool interior = (base >= 0) && (base + 4 * (LPT - 1) + 31 < LIN);

    if (interior) {
        for (int ci = 0; ci < CIN; ++ci) {
            const float* ip = inb + ci * ISTR + base;
            float4 v[NV];
#pragma unroll
            for (int k = 0; k < NV; ++k) v[k] = *(const float4*)(ip + 4 * k);
#pragma unroll
            for (int k4 = 0; k4 < 8; ++k4) {
#pragma unroll
                for (int c = 0; c < CPT; ++c) {
                    const float* wk = &w_s[((co0 + c) * CIN + ci) * 32 + 4 * k4];
                    float wx = wk[0], wy = wk[1], wz = wk[2], ww = wk[3];
#pragma unroll
                    for (int j = 0; j < LPT; ++j)
                        acc[c][j] += v[k4 + j].x * wx + v[k4 + j].y * wy
                                   + v[k4 + j].z * wz + v[k4 + j].w * ww;
                }
            }
        }
    } else {
#pragma unroll
        for (int j = 0; j < LPT; ++j) {
            int l = l0 + j;
            if (l < LOUT) {
                int bs = 4 * l - 16;
                for (int ci = 0; ci < CIN; ++ci) {
                    const float* ip = inb + ci * ISTR;
                    for (int k = 0; k < 32; ++k) {
                        int pos = bs + k;
                        float xv = (pos >= 0 && pos < LIN) ? ip[pos] : 0.f;
#pragma unroll
                        for (int c = 0; c < CPT; ++c)
                            acc[c][j] += xv * w_s[((co0 + c) * CIN + ci) * 32 + k];
                    }
                }
            }
        }
    }

#pragma unroll
    for (int c = 0; c < CPT; ++c) {
        int co = co0 + c;
        if constexpr (CONCAT) {
            // b = i*32 + batch; feats[batch][i*1040 + co*65 + l]
            if (l0 < LOUT)
                out[(size_t)(b & 31) * 2080 + (b >> 5) * 1040 + co * 65 + l0] =
                    tanhf(acc[c][0]);
        } else if constexpr (LPT == 1) {
            if (l0 < LOUT)
                out[((size_t)b * COUT + co) * OSTR + l0] = tanhf(acc[c][0]);
        } else {
            size_t row = ((size_t)b * COUT + co) * OSTR;
            if (l0 + 1 < LOUT) {
                float2 st = make_float2(tanhf(acc[c][0]), tanhf(acc[c][1]));
                *(float2*)&out[row + l0] = st;
            } else if (l0 < LOUT) {
                out[row + l0] = tanhf(acc[c][0]);
            }
        }
    }
}

// =====================================================================
// fc1: (32,2080) @ (128,2080)^T + b -> tanh. One wave per output, f-parallel.
// =====================================================================
__global__ __launch_bounds__(256) void fc1_kernel(const float* __restrict__ h,
                                                  const float* __restrict__ w,
                                                  const float* __restrict__ bias,
                                                  float* __restrict__ out)
{
    int lane = threadIdx.x & 63;
    int wid = blockIdx.x * 4 + (threadIdx.x >> 6);  // 0..1023
#pragma unroll
    for (int r = 0; r < 4; ++r) {
        int o = wid + r * 1024;   // 0..4095
        int b = o >> 7;
        int j = o & 127;
        const float* hb = h + (size_t)b * 2080;
        const float* wj = w + (size_t)j * 2080;
        float acc = 0.f;
        for (int f = lane; f < 2080; f += 64) acc += hb[f] * wj[f];
        for (int off = 32; off; off >>= 1) acc += __shfl_down(acc, off, 64);
        if (lane == 0) out[b * 128 + j] = tanhf(acc + bias[j]);
    }
}

// =====================================================================
// fc2: (32,128) @ (16,128)^T + b -> tanh. One wave per output.
// =====================================================================
__global__ __launch_bounds__(256) void fc2_kernel(const float* __restrict__ h,
                                                  const float* __restrict__ w,
                                                  const float* __restrict__ bias,
                                                  float* __restrict__ out)
{
    int lane = threadIdx.x & 63;
    int o = blockIdx.x * 4 + (threadIdx.x >> 6);  // 0..511
    int b = o >> 4;
    int j = o & 15;
    const float* hb = h + (size_t)b * 128;
    const float* wj = w + (size_t)j * 128;
    float acc = hb[lane] * wj[lane] + hb[lane + 64] * wj[lane + 64];
    for (int off = 32; off; off >>= 1) acc += __shfl_down(acc, off, 64);
    if (lane == 0) out[o] = tanhf(acc + bias[j]);
}

extern "C" void kernel_launch(void* const* d_in, const int* in_sizes, int n_in,
                              void* d_out, int out_size, void* d_ws, size_t ws_size,
                              hipStream_t stream)
{
    const float* x = (const float*)d_in[0];
    const int* orderings = (const int*)d_in[1];
    const float* sp_w = (const float*)d_in[2];
    const float* sp_b = (const float*)d_in[3];
    const float* conv_w[5];
    const float* conv_b[5];
    for (int j = 0; j < 5; ++j) {
        conv_w[j] = (const float*)d_in[4 + 2 * j];
        conv_b[j] = (const float*)d_in[5 + 2 * j];
    }
    const float* fc1_w = (const float*)d_in[14];
    const float* fc1_b = (const float*)d_in[15];
    const float* fc2_w = (const float*)d_in[16];
    const float* fc2_b = (const float*)d_in[17];

    float* ws = (float*)d_ws;

    // 1) transpose x -> x_t at ws[0..4194304)
    transpose_kernel<<<NPTS / 64, 256, 0, stream>>>(x, ws);

    if (ws_size >= 16778240ull * 4ull) {
        // ---------- big-ws path: merged batch B=64 ----------
        // layout (floats): xt [0,4194304) ; s [4194304,12582912) ;
        //   c0 [12582912,16778240) ; c1/c2/c3/feats/h1 reuse xt region.
        size_t o_s = 4194304, o_c0 = 12582912;
        size_t o_c1 = 0, o_c2 = 2099200, o_c3 = 3151872, o_f = 3418112, o_h1 = 3484672;

        smooth_kernel<<<512, 256, 0, stream>>>(ws, orderings, sp_w, sp_b, ws + o_s);
        smooth_kernel<<<512, 256, 0, stream>>>(ws, orderings + NPTS, sp_w, sp_b,
                                               ws + o_s + 4194304);

        conv_direct<2, 4, 4, 256, 2, 65536, 16388, 65536, 16385, false>
            <<<64 * 33, 256, 0, stream>>>(ws + o_s, conv_w[0], conv_b[0], ws + o_c0);
        conv_direct<4, 8, 8, 256, 2, 16388, 4100, 16385, 4097, false>
            <<<64 * 9, 256, 0, stream>>>(ws + o_c0, conv_w[1], conv_b[1], ws + o_c1);
        conv_direct<8, 16, 8, 128, 2, 4100, 1028, 4097, 1025, false>
            <<<64 * 5, 256, 0, stream>>>(ws + o_c1, conv_w[2], conv_b[2], ws + o_c2);
        conv_direct<16, 16, 8, 128, 1, 1028, 260, 1025, 257, false>
            <<<64 * 3, 256, 0, stream>>>(ws + o_c2, conv_w[3], conv_b[3], ws + o_c3);
        conv_direct<16, 16, 4, 64, 1, 260, 0, 257, 65, true>
            <<<64 * 2, 256, 0, stream>>>(ws + o_c3, conv_w[4], conv_b[4], ws + o_f);

        fc1_kernel<<<256, 256, 0, stream>>>(ws + o_f, fc1_w, fc1_b, ws + o_h1);
        fc2_kernel<<<128, 256, 0, stream>>>(ws + o_h1, fc2_w, fc2_b, (float*)d_out);
    } else {
        // ---------- small-ws path: per-SFC pipeline, B=32 (49.1 MB) ----------
        size_t o_s = 4194304, o_c0 = 8388608, o_c1 = 10486272, o_c2 = 11535872,
               o_c3 = 12062208, o_f = 12195328, o_h1 = 12261888;

        for (int i = 0; i < 2; ++i) {
            smooth_kernel<<<512, 256, 0, stream>>>(ws, orderings + (size_t)i * NPTS,
                                                   sp_w, sp_b, ws + o_s);
            conv_direct<2, 4, 4, 256, 2, 65536, 16388, 65536, 16385, false>
                <<<32 * 33, 256, 0, stream>>>(ws + o_s, conv_w[0], conv_b[0], ws + o_c0);
            conv_direct<4, 8, 8, 256, 2, 16388, 4100, 16385, 4097, false>
                <<<32 * 9, 256, 0, stream>>>(ws + o_c0, conv_w[1], conv_b[1], ws + o_c1);
            conv_direct<8, 16, 8, 128, 2, 4100, 1028, 4097, 1025, false>
                <<<32 * 5, 256, 0, stream>>>(ws + o_c1, conv_w[2], conv_b[2], ws + o_c2);
            conv_direct<16, 16, 8, 128, 1, 1028, 260, 1025, 257, false>
                <<<32 * 3, 256, 0, stream>>>(ws + o_c2, conv_w[3], conv_b[3], ws + o_c3);
            conv_direct<16, 16, 4, 64, 1, 260, 0, 257, 65, true>
                <<<32 * 2, 256, 0, stream>>>(ws + o_c3, conv_w[4], conv_b[4],
                                             ws + o_f + (size_t)i * 1040);
        }
        fc1_kernel<<<256, 256, 0, stream>>>(ws + o_f, fc1_w, fc1_b, ws + o_h1);
        fc2_kernel<<<128, 256, 0, stream>>>(ws + o_h1, fc2_w, fc2_b, (float*)d_out);
    }
}

// Round 7
// 316.136 us; speedup vs baseline: 4.3930x; 4.3930x over previous
//
#include <hip/hip_runtime.h>
#include <math.h>

#define NPTS 65536
#define BATCH 32

// =====================================================================
// transpose x (B,N,2) -> x_t (N, 64)  [x_t[n][b*2+c] = x[b][n][c]]
// =====================================================================
__global__ __launch_bounds__(256) void transpose_kernel(const float* __restrict__ x,
                                                        float* __restrict__ xt)
{
    __shared__ float tile[64][65];
    int n0 = blockIdx.x * 64;
    int tid = threadIdx.x;
    int lane = tid & 63, w = tid >> 6;
    const float2* x2 = (const float2*)x;
#pragma unroll
    for (int bq = 0; bq < 8; ++bq) {
        int b = bq * 4 + w;
        float2 v = x2[(size_t)b * NPTS + n0 + lane];
        tile[lane][b * 2 + 0] = v.x;
        tile[lane][b * 2 + 1] = v.y;
    }
    __syncthreads();
    int f4 = tid & 15;
#pragma unroll
    for (int rq = 0; rq < 4; ++rq) {
        int r = rq * 16 + (tid >> 4);
        float4 v = make_float4(tile[r][f4 * 4 + 0], tile[r][f4 * 4 + 1],
                               tile[r][f4 * 4 + 2], tile[r][f4 * 4 + 3]);
        *(float4*)&xt[(size_t)(n0 + r) * 64 + f4 * 4] = v;
    }
}

// =====================================================================
// smooth (one SFC): s[(b*2+c)*N + n] = tanh(sum_k xt[ord[clip(n-1+k)]][b*2+c]*sp_w[n,k]+sp_b[n])
// =====================================================================
__global__ __launch_bounds__(256) void smooth_kernel(const float* __restrict__ xt,
                                                     const int* __restrict__ ord,
                                                     const float* __restrict__ sp_w,
                                                     const float* __restrict__ sp_b,
                                                     float* __restrict__ s)
{
    __shared__ int s_idx[130];
    __shared__ float rows[130][65];
    int n0 = blockIdx.x * 128;
    int tid = threadIdx.x;
    if (tid < 130) {
        int g = n0 - 1 + tid;
        g = g < 0 ? 0 : (g > NPTS - 1 ? NPTS - 1 : g);
        s_idx[tid] = ord[g];
    }
    __syncthreads();
    for (int q = tid; q < 130 * 16; q += 256) {
        int r = q >> 4, f4 = q & 15;
        float4 v = *(const float4*)&xt[(size_t)s_idx[r] * 64 + f4 * 4];
        rows[r][f4 * 4 + 0] = v.x; rows[r][f4 * 4 + 1] = v.y;
        rows[r][f4 * 4 + 2] = v.z; rows[r][f4 * 4 + 3] = v.w;
    }
    __syncthreads();
    int n_local = tid & 127, half = tid >> 7;
    int n = n0 + n_local;
    float w0 = sp_w[n * 3 + 0], w1 = sp_w[n * 3 + 1], w2 = sp_w[n * 3 + 2];
    float bb = sp_b[n];
#pragma unroll 4
    for (int bc = 0; bc < 64; bc += 2) {
        int bce = bc + half;
        float v = w0 * rows[n_local][bce] + w1 * rows[n_local + 1][bce]
                + w2 * rows[n_local + 2][bce] + bb;
        s[(size_t)bce * NPTS + n] = tanhf(v);
    }
}

// =====================================================================
// Sliding-window direct conv1d + bias + tanh. No LDS, no __syncthreads.
//  - grid block = (b, tile, cg): channel group in blockIdx -> co0 block-uniform
//    -> weight/bias reads are wave-uniform scalar loads (SGPR operands).
//  - interior threads: NV=8+LPT-1 aligned float4 loads per ci, shared across
//    LPT outputs and CPT channels. #pragma unroll 1 on ci: ONE window live.
//  - rows padded (ISTR/OSTR mult of 4) so all float4 accesses are 16B-aligned.
// =====================================================================
template <int CIN, int COUT, int CPT, int LPT, int ISTR, int OSTR,
          int LIN, int LOUT, bool CONCAT>
__global__ __launch_bounds__(256, 2) void conv_sw(
    const float* __restrict__ in,      // (B, CIN, ISTR)
    const float* __restrict__ w,       // (COUT, CIN, 32)
    const float* __restrict__ bias,    // (COUT,)
    float* __restrict__ out)
{
    constexpr int G = COUT / CPT;          // channel groups (in grid)
    constexpr int SPANL = 256 * LPT;       // outputs per block
    constexpr int NT = (LOUT + SPANL - 1) / SPANL;
    constexpr int NV = 8 + LPT - 1;        // float4s in sliding window

    int bid = blockIdx.x;
    int cg = bid % G;
    int t2 = bid / G;
    int tile = t2 % NT;
    int b = t2 / NT;
    int tid = threadIdx.x;

    int l0 = tile * SPANL + tid * LPT;
    int co0 = cg * CPT;

    float acc[CPT][LPT];
#pragma unroll
    for (int c = 0; c < CPT; ++c) {
        float bv = bias[co0 + c];
#pragma unroll
        for (int j = 0; j < LPT; ++j) acc[c][j] = bv;
    }

    const float* inb = in + (size_t)b * CIN * ISTR;
    int base = 4 * l0 - 16;

    if (base >= 0 && base + NV * 4 <= LIN) {
        // ---- interior: all taps in-bounds, unguarded aligned float4s ----
#pragma unroll 1
        for (int ci = 0; ci < CIN; ++ci) {
            const float* ip = inb + ci * ISTR + base;
            float4 v[NV];
#pragma unroll
            for (int k = 0; k < NV; ++k) v[k] = *(const float4*)(ip + 4 * k);
            const float* wci = w + (size_t)(co0 * CIN + ci) * 32;
#pragma unroll
            for (int k4 = 0; k4 < 8; ++k4) {
#pragma unroll
                for (int c = 0; c < CPT; ++c) {
                    const float* wk = wci + (size_t)c * CIN * 32 + 4 * k4;
                    float wx = wk[0], wy = wk[1], wz = wk[2], ww = wk[3];
#pragma unroll
                    for (int j = 0; j < LPT; ++j)
                        acc[c][j] += v[k4 + j].x * wx + v[k4 + j].y * wy
                                   + v[k4 + j].z * wz + v[k4 + j].w * ww;
                }
            }
        }
    } else {
        // ---- edge: scalar guarded taps ----
#pragma unroll 1
        for (int ci = 0; ci < CIN; ++ci) {
            const float* ip = inb + ci * ISTR;
            const float* wci = w + (size_t)(co0 * CIN + ci) * 32;
#pragma unroll
            for (int j = 0; j < LPT; ++j) {
                int l = l0 + j;
                if (l < LOUT) {
                    int bs = 4 * l - 16;
                    for (int k = 0; k < 32; ++k) {
                        int pos = bs + k;
                        float xv = (pos >= 0 && pos < LIN) ? ip[pos] : 0.f;
#pragma unroll
                        for (int c = 0; c < CPT; ++c)
                            acc[c][j] += xv * wci[(size_t)c * CIN * 32 + k];
                    }
                }
            }
        }
    }

#pragma unroll
    for (int c = 0; c < CPT; ++c) {
        int co = co0 + c;
        if constexpr (CONCAT) {
            // b = i*32 + batch; feats[batch][i*1040 + co*65 + l0]
            if (l0 < LOUT)
                out[(size_t)(b & 31) * 2080 + (b >> 5) * 1040 + co * 65 + l0] =
                    tanhf(acc[c][0]);
        } else {
            size_t row = ((size_t)b * COUT + co) * OSTR;
            if (l0 + LPT <= LOUT) {
                if constexpr (LPT == 4) {
                    float4 st = make_float4(tanhf(acc[c][0]), tanhf(acc[c][1]),
                                            tanhf(acc[c][2]), tanhf(acc[c][3]));
                    *(float4*)&out[row + l0] = st;
                } else if constexpr (LPT == 2) {
                    float2 st = make_float2(tanhf(acc[c][0]), tanhf(acc[c][1]));
                    *(float2*)&out[row + l0] = st;
                } else {
                    out[row + l0] = tanhf(acc[c][0]);
                }
            } else {
#pragma unroll
                for (int j = 0; j < LPT; ++j)
                    if (l0 + j < LOUT) out[row + l0 + j] = tanhf(acc[c][j]);
            }
        }
    }
}

// =====================================================================
// fc1: (32,2080) @ (128,2080)^T + b -> tanh. One wave per output, f-parallel.
// =====================================================================
__global__ __launch_bounds__(256) void fc1_kernel(const float* __restrict__ h,
                                                  const float* __restrict__ w,
                                                  const float* __restrict__ bias,
                                                  float* __restrict__ out)
{
    int lane = threadIdx.x & 63;
    int wid = blockIdx.x * 4 + (threadIdx.x >> 6);  // 0..1023
#pragma unroll
    for (int r = 0; r < 4; ++r) {
        int o = wid + r * 1024;   // 0..4095
        int b = o >> 7;
        int j = o & 127;
        const float* hb = h + (size_t)b * 2080;
        const float* wj = w + (size_t)j * 2080;
        float acc = 0.f;
        for (int f = lane; f < 2080; f += 64) acc += hb[f] * wj[f];
        for (int off = 32; off; off >>= 1) acc += __shfl_down(acc, off, 64);
        if (lane == 0) out[b * 128 + j] = tanhf(acc + bias[j]);
    }
}

// =====================================================================
// fc2: (32,128) @ (16,128)^T + b -> tanh. One wave per output.
// =====================================================================
__global__ __launch_bounds__(256) void fc2_kernel(const float* __restrict__ h,
                                                  const float* __restrict__ w,
                                                  const float* __restrict__ bias,
                                                  float* __restrict__ out)
{
    int lane = threadIdx.x & 63;
    int o = blockIdx.x * 4 + (threadIdx.x >> 6);  // 0..511
    int b = o >> 4;
    int j = o & 15;
    const float* hb = h + (size_t)b * 128;
    const float* wj = w + (size_t)j * 128;
    float acc = hb[lane] * wj[lane] + hb[lane + 64] * wj[lane + 64];
    for (int off = 32; off; off >>= 1) acc += __shfl_down(acc, off, 64);
    if (lane == 0) out[o] = tanhf(acc + bias[j]);
}

extern "C" void kernel_launch(void* const* d_in, const int* in_sizes, int n_in,
                              void* d_out, int out_size, void* d_ws, size_t ws_size,
                              hipStream_t stream)
{
    const float* x = (const float*)d_in[0];
    const int* orderings = (const int*)d_in[1];
    const float* sp_w = (const float*)d_in[2];
    const float* sp_b = (const float*)d_in[3];
    const float* conv_w[5];
    const float* conv_b[5];
    for (int j = 0; j < 5; ++j) {
        conv_w[j] = (const float*)d_in[4 + 2 * j];
        conv_b[j] = (const float*)d_in[5 + 2 * j];
    }
    const float* fc1_w = (const float*)d_in[14];
    const float* fc1_b = (const float*)d_in[15];
    const float* fc2_w = (const float*)d_in[16];
    const float* fc2_b = (const float*)d_in[17];

    float* ws = (float*)d_ws;

    // 1) transpose x -> x_t at ws[0..4194304)
    transpose_kernel<<<NPTS / 64, 256, 0, stream>>>(x, ws);

    if (ws_size >= 16778240ull * 4ull) {
        // ---------- big-ws path: merged batch B=64 ----------
        // floats: xt [0,4194304) ; s [4194304,12582912) ; c0 [12582912,16778240)
        //         c1/c2/c3/feats/h1 reuse the xt region.
        size_t o_s = 4194304, o_c0 = 12582912;
        size_t o_c1 = 0, o_c2 = 2099200, o_c3 = 3151872, o_f = 3418112, o_h1 = 3484672;

        smooth_kernel<<<512, 256, 0, stream>>>(ws, orderings, sp_w, sp_b, ws + o_s);
        smooth_kernel<<<512, 256, 0, stream>>>(ws, orderings + NPTS, sp_w, sp_b,
                                               ws + o_s + 4194304);

        // conv0: CPT=4 (G=1), LPT=4, NT=17  grid 64*17*1
        conv_sw<2, 4, 4, 4, 65536, 16388, 65536, 16385, false>
            <<<1088, 256, 0, stream>>>(ws + o_s, conv_w[0], conv_b[0], ws + o_c0);
        // conv1: CPT=4 (G=2), LPT=4, NT=5   grid 64*5*2
        conv_sw<4, 8, 4, 4, 16388, 4100, 16385, 4097, false>
            <<<640, 256, 0, stream>>>(ws + o_c0, conv_w[1], conv_b[1], ws + o_c1);
        // conv2: CPT=4 (G=4), LPT=2, NT=3   grid 64*3*4
        conv_sw<8, 16, 4, 2, 4100, 1028, 4097, 1025, false>
            <<<768, 256, 0, stream>>>(ws + o_c1, conv_w[2], conv_b[2], ws + o_c2);
        // conv3: CPT=2 (G=8), LPT=1, NT=2   grid 64*2*8
        conv_sw<16, 16, 2, 1, 1028, 260, 1025, 257, false>
            <<<1024, 256, 0, stream>>>(ws + o_c2, conv_w[3], conv_b[3], ws + o_c3);
        // conv4: CPT=2 (G=8), LPT=1, NT=1, CONCAT  grid 64*1*8
        conv_sw<16, 16, 2, 1, 260, 0, 257, 65, true>
            <<<512, 256, 0, stream>>>(ws + o_c3, conv_w[4], conv_b[4], ws + o_f);

        fc1_kernel<<<256, 256, 0, stream>>>(ws + o_f, fc1_w, fc1_b, ws + o_h1);
        fc2_kernel<<<128, 256, 0, stream>>>(ws + o_h1, fc2_w, fc2_b, (float*)d_out);
    } else {
        // ---------- small-ws path: per-SFC pipeline, B=32 (49.1 MB) ----------
        size_t o_s = 4194304, o_c0 = 8388608, o_c1 = 10486272, o_c2 = 11535872,
               o_c3 = 12062208, o_f = 12195328, o_h1 = 12261888;

        for (int i = 0; i < 2; ++i) {
            smooth_kernel<<<512, 256, 0, stream>>>(ws, orderings + (size_t)i * NPTS,
                                                   sp_w, sp_b, ws + o_s);
            conv_sw<2, 4, 4, 4, 65536, 16388, 65536, 16385, false>
                <<<544, 256, 0, stream>>>(ws + o_s, conv_w[0], conv_b[0], ws + o_c0);
            conv_sw<4, 8, 4, 4, 16388, 4100, 16385, 4097, false>
                <<<320, 256, 0, stream>>>(ws + o_c0, conv_w[1], conv_b[1], ws + o_c1);
            conv_sw<8, 16, 4, 2, 4100, 1028, 4097, 1025, false>
                <<<384, 256, 0, stream>>>(ws + o_c1, conv_w[2], conv_b[2], ws + o_c2);
            conv_sw<16, 16, 2, 1, 1028, 260, 1025, 257, false>
                <<<512, 256, 0, stream>>>(ws + o_c2, conv_w[3], conv_b[3], ws + o_c3);
            conv_sw<16, 16, 2, 1, 260, 0, 257, 65, true>
                <<<256, 256, 0, stream>>>(ws + o_c3, conv_w[4], conv_b[4],
                                          ws + o_f + (size_t)i * 1040);
        }
        fc1_kernel<<<256, 256, 0, stream>>>(ws + o_f, fc1_w, fc1_b, ws + o_h1);
        fc2_kernel<<<128, 256, 0, stream>>>(ws + o_h1, fc2_w, fc2_b, (float*)d_out);
    }
}

// Round 8
// 224.918 us; speedup vs baseline: 6.1747x; 1.4056x over previous
//
#include <hip/hip_runtime.h>
#include <math.h>

#define NPTS 65536

__device__ __forceinline__ float4 ld4_guard(const float* __restrict__ row, int pos, int hi) {
    float4 v;
    if (pos >= 0 && pos + 4 <= hi) {
        v = *(const float4*)(row + pos);
    } else {
        v.x = (pos + 0 >= 0 && pos + 0 < hi) ? row[pos + 0] : 0.f;
        v.y = (pos + 1 >= 0 && pos + 1 < hi) ? row[pos + 1] : 0.f;
        v.z = (pos + 2 >= 0 && pos + 2 < hi) ? row[pos + 2] : 0.f;
        v.w = (pos + 3 >= 0 && pos + 3 < hi) ? row[pos + 3] : 0.f;
    }
    return v;
}

// =====================================================================
// transpose x (B,N,2) -> x_t (N, 64)  [x_t[n][b*2+c] = x[b][n][c]]
// =====================================================================
__global__ __launch_bounds__(256) void transpose_kernel(const float* __restrict__ x,
                                                        float* __restrict__ xt)
{
    __shared__ float tile[64][65];
    int n0 = blockIdx.x * 64;
    int tid = threadIdx.x;
    int lane = tid & 63, w = tid >> 6;
    const float2* x2 = (const float2*)x;
#pragma unroll
    for (int bq = 0; bq < 8; ++bq) {
        int b = bq * 4 + w;
        float2 v = x2[(size_t)b * NPTS + n0 + lane];
        tile[lane][b * 2 + 0] = v.x;
        tile[lane][b * 2 + 1] = v.y;
    }
    __syncthreads();
    int f4 = tid & 15;
#pragma unroll
    for (int rq = 0; rq < 4; ++rq) {
        int r = rq * 16 + (tid >> 4);
        float4 v = make_float4(tile[r][f4 * 4 + 0], tile[r][f4 * 4 + 1],
                               tile[r][f4 * 4 + 2], tile[r][f4 * 4 + 3]);
        *(float4*)&xt[(size_t)(n0 + r) * 64 + f4 * 4] = v;
    }
}

// =====================================================================
// smooth (one SFC): s[(b*2+c)*N + n] = tanh(sum_k xt[ord[clip(n-1+k)]][b*2+c]*sp_w[n,k]+sp_b[n])
// =====================================================================
__global__ __launch_bounds__(256) void smooth_kernel(const float* __restrict__ xt,
                                                     const int* __restrict__ ord,
                                                     const float* __restrict__ sp_w,
                                                     const float* __restrict__ sp_b,
                                                     float* __restrict__ s)
{
    __shared__ int s_idx[130];
    __shared__ float rows[130][65];
    int n0 = blockIdx.x * 128;
    int tid = threadIdx.x;
    if (tid < 130) {
        int g = n0 - 1 + tid;
        g = g < 0 ? 0 : (g > NPTS - 1 ? NPTS - 1 : g);
        s_idx[tid] = ord[g];
    }
    __syncthreads();
    for (int q = tid; q < 130 * 16; q += 256) {
        int r = q >> 4, f4 = q & 15;
        float4 v = *(const float4*)&xt[(size_t)s_idx[r] * 64 + f4 * 4];
        rows[r][f4 * 4 + 0] = v.x; rows[r][f4 * 4 + 1] = v.y;
        rows[r][f4 * 4 + 2] = v.z; rows[r][f4 * 4 + 3] = v.w;
    }
    __syncthreads();
    int n_local = tid & 127, half = tid >> 7;
    int n = n0 + n_local;
    float w0 = sp_w[n * 3 + 0], w1 = sp_w[n * 3 + 1], w2 = sp_w[n * 3 + 2];
    float bb = sp_b[n];
#pragma unroll 4
    for (int bc = 0; bc < 64; bc += 2) {
        int bce = bc + half;
        float v = w0 * rows[n_local][bce] + w1 * rows[n_local + 1][bce]
                + w2 * rows[n_local + 2][bce] + bb;
        s[(size_t)bce * NPTS + n] = tanhf(v);
    }
}

// =====================================================================
// LDS-staged conv (conv0 / conv1): float4 staging, LPT=2 sliding outputs,
// all COUT channels per thread, weights in LDS (broadcast reads).
// unroll(1) on ci: exactly one 9-float4 window live -> no spill.
// =====================================================================
template <int CIN, int COUT, int LPT, int ISTR, int OSTR, int LIN, int LOUT>
__global__ __launch_bounds__(256, 2) void conv_lds(
    const float* __restrict__ in,      // (B, CIN, ISTR)
    const float* __restrict__ w,       // (COUT, CIN, 32)
    const float* __restrict__ bias,
    float* __restrict__ out)           // (B, COUT, OSTR)
{
    constexpr int LTILE = 256 * LPT;
    constexpr int SPAN = 4 * LTILE + 28;     // divisible by 4
    constexpr int NF4 = SPAN / 4;
    constexpr int NT = (LOUT + LTILE - 1) / LTILE;
    constexpr int NV = 8 + LPT - 1;

    __shared__ float in_s[CIN][SPAN];
    __shared__ float w_s[COUT][CIN][32];

    int bid = blockIdx.x;
    int tile = bid % NT;
    int b = bid / NT;
    int tid = threadIdx.x;

    for (int i = tid; i < COUT * CIN * 32; i += 256)
        ((float*)w_s)[i] = w[i];

    int base = tile * LTILE * 4 - 16;
    const float* inb = in + (size_t)b * CIN * ISTR;
    if (base >= 0 && base + SPAN <= LIN) {
        for (int q = tid; q < CIN * NF4; q += 256) {
            int ci = q / NF4, p = q - ci * NF4;
            *(float4*)&in_s[ci][4 * p] =
                *(const float4*)(inb + (size_t)ci * ISTR + base + 4 * p);
        }
    } else {
        for (int q = tid; q < CIN * SPAN; q += 256) {
            int ci = q / SPAN, p = q - ci * SPAN;
            int pos = base + p;
            in_s[ci][p] = (pos >= 0 && pos < LIN) ? inb[(size_t)ci * ISTR + pos] : 0.f;
        }
    }
    __syncthreads();

    int lofs = tid * LPT;
    float acc[COUT][LPT];
#pragma unroll
    for (int c = 0; c < COUT; ++c) {
        float bv = bias[c];
#pragma unroll
        for (int j = 0; j < LPT; ++j) acc[c][j] = bv;
    }

#pragma unroll 1
    for (int ci = 0; ci < CIN; ++ci) {
        float4 v[NV];
#pragma unroll
        for (int k = 0; k < NV; ++k)
            v[k] = *(const float4*)&in_s[ci][4 * lofs + 4 * k];
#pragma unroll
        for (int k4 = 0; k4 < 8; ++k4) {
#pragma unroll
            for (int c = 0; c < COUT; ++c) {
                const float* wk = &w_s[c][ci][4 * k4];
                float wx = wk[0], wy = wk[1], wz = wk[2], ww = wk[3];
#pragma unroll
                for (int j = 0; j < LPT; ++j)
                    acc[c][j] += v[k4 + j].x * wx + v[k4 + j].y * wy
                               + v[k4 + j].z * wz + v[k4 + j].w * ww;
            }
        }
    }

    int l0 = tile * LTILE + lofs;
#pragma unroll
    for (int c = 0; c < COUT; ++c) {
        size_t row = ((size_t)b * COUT + c) * OSTR;
        if (l0 + 1 < LOUT) {
            float2 st2 = make_float2(tanhf(acc[c][0]), tanhf(acc[c][1]));
            *(float2*)&out[row + l0] = st2;
        } else if (l0 < LOUT) {
            out[row + l0] = tanhf(acc[c][0]);
        }
    }
}

// =====================================================================
// Fused conv2+conv3. Block = (b, t3) with t3 in [0,4): l3 range t3*65..+64.
// Stage conv1-out span (8 x 1180) in LDS -> conv2 (16 x 288) into LDS
// (never touches HBM) -> conv3 -> c3out (padded rows of 260).
// =====================================================================
__global__ __launch_bounds__(256) void conv23_kernel(
    const float* __restrict__ c1,      // (B, 8, 4100), LIN 4097
    const float* __restrict__ w2, const float* __restrict__ b2,
    const float* __restrict__ w3, const float* __restrict__ b3,
    float* __restrict__ c3out)         // (B, 16, 260), valid l3 < 257
{
    __shared__ float st[8][1184];
    __shared__ float c2s[16][292];
    __shared__ float w2s[16][8][32];
    __shared__ float w3s[16][16][32];

    int b = blockIdx.x >> 2;
    int t3 = blockIdx.x & 3;
    int tid = threadIdx.x;

    for (int i = tid; i < 16 * 8 * 32; i += 256) ((float*)w2s)[i] = w2[i];
    for (int i = tid; i < 16 * 16 * 32; i += 256) ((float*)w3s)[i] = w3[i];

    int gbase = 1040 * t3 - 80;
    const float* c1b = c1 + (size_t)b * 8 * 4100;
    for (int q = tid; q < 8 * 295; q += 256) {
        int ci = q / 295, p = q - ci * 295;
        float4 v = ld4_guard(c1b + (size_t)ci * 4100, gbase + 4 * p, 4097);
        *(float4*)&st[ci][4 * p] = v;
    }
    __syncthreads();

    // conv2: i in [0,288), l2 = 260*t3 - 16 + i ; window local idx = 4*i + k
    for (int i0 = 0; i0 < 288; i0 += 256) {
        int i = i0 + tid;
        if (i < 288) {
            int l2 = 260 * t3 - 16 + i;
            bool valid = (l2 >= 0) && (l2 < 1025);
#pragma unroll
            for (int coh = 0; coh < 2; ++coh) {
                float acc[8];
#pragma unroll
                for (int c = 0; c < 8; ++c) acc[c] = b2[coh * 8 + c];
#pragma unroll 1
                for (int ci = 0; ci < 8; ++ci) {
                    float4 v[8];
#pragma unroll
                    for (int k = 0; k < 8; ++k)
                        v[k] = *(const float4*)&st[ci][4 * i + 4 * k];
#pragma unroll
                    for (int k4 = 0; k4 < 8; ++k4) {
#pragma unroll
                        for (int c = 0; c < 8; ++c) {
                            const float* wk = &w2s[coh * 8 + c][ci][4 * k4];
                            acc[c] += v[k4].x * wk[0] + v[k4].y * wk[1]
                                    + v[k4].z * wk[2] + v[k4].w * wk[3];
                        }
                    }
                }
#pragma unroll
                for (int c = 0; c < 8; ++c)
                    c2s[coh * 8 + c][i] = valid ? tanhf(acc[c]) : 0.f;
            }
        }
    }
    __syncthreads();

    // conv3: l3 = t3*65 + l3loc, input local idx = 4*l3loc + k
    for (int q = tid; q < 1040; q += 256) {
        int co = q / 65, l3loc = q - co * 65;
        int l3 = t3 * 65 + l3loc;
        if (l3 < 257) {
            float acc = b3[co];
#pragma unroll 1
            for (int ci = 0; ci < 16; ++ci) {
#pragma unroll
                for (int k4 = 0; k4 < 8; ++k4) {
                    float4 v = *(const float4*)&c2s[ci][4 * l3loc + 4 * k4];
                    const float* wk = &w3s[co][ci][4 * k4];
                    acc += v.x * wk[0] + v.y * wk[1] + v.z * wk[2] + v.w * wk[3];
                }
            }
            c3out[((size_t)b * 16 + co) * 260 + l3] = tanhf(acc);
        }
    }
}

// =====================================================================
// conv4 + concat into feats. One block per b.
// =====================================================================
__global__ __launch_bounds__(256) void conv4_kernel(
    const float* __restrict__ c3,      // (B, 16, 260), valid l3 < 257
    const float* __restrict__ w4, const float* __restrict__ b4,
    float* __restrict__ feats, int ibase)
{
    __shared__ float st[16][288];
    __shared__ float w4s[16][16][32];
    int b = blockIdx.x, tid = threadIdx.x;
    for (int i = tid; i < 16 * 16 * 32; i += 256) ((float*)w4s)[i] = w4[i];
    const float* c3b = c3 + (size_t)b * 16 * 260;
    for (int q = tid; q < 16 * 72; q += 256) {
        int ci = q / 72, p = q - ci * 72;
        float4 v = ld4_guard(c3b + (size_t)ci * 260, 4 * p - 16, 257);
        *(float4*)&st[ci][4 * p] = v;
    }
    __syncthreads();
    for (int q = tid; q < 1040; q += 256) {
        int co = q / 65, l4 = q - co * 65;
        float acc = b4[co];
#pragma unroll 1
        for (int ci = 0; ci < 16; ++ci) {
#pragma unroll
            for (int k4 = 0; k4 < 8; ++k4) {
                float4 v = *(const float4*)&st[ci][4 * l4 + 4 * k4];
                const float* wk = &w4s[co][ci][4 * k4];
                acc += v.x * wk[0] + v.y * wk[1] + v.z * wk[2] + v.w * wk[3];
            }
        }
        feats[(size_t)(b & 31) * 2080 + (size_t)((b >> 5) + ibase) * 1040 + co * 65 + l4]
            = tanhf(acc);
    }
}

// =====================================================================
// fc1: (32,2080) @ (128,2080)^T + b -> tanh. Wave per output, float4 dots.
// =====================================================================
__global__ __launch_bounds__(256) void fc1_kernel(const float* __restrict__ h,
                                                  const float* __restrict__ w,
                                                  const float* __restrict__ bias,
                                                  float* __restrict__ out)
{
    int lane = threadIdx.x & 63;
    int wid = blockIdx.x * 4 + (threadIdx.x >> 6);  // 0..1023
#pragma unroll
    for (int r = 0; r < 4; ++r) {
        int o = wid + r * 1024;
        int b = o >> 7, j = o & 127;
        const float4* h4 = (const float4*)(h + (size_t)b * 2080);
        const float4* w4 = (const float4*)(w + (size_t)j * 2080);
        float acc = 0.f;
#pragma unroll
        for (int q = 0; q < 8; ++q) {
            float4 a = h4[lane + 64 * q], c = w4[lane + 64 * q];
            acc += a.x * c.x + a.y * c.y + a.z * c.z + a.w * c.w;
        }
        if (lane < 8) {
            float4 a = h4[512 + lane], c = w4[512 + lane];
            acc += a.x * c.x + a.y * c.y + a.z * c.z + a.w * c.w;
        }
        for (int off = 32; off; off >>= 1) acc += __shfl_down(acc, off, 64);
        if (lane == 0) out[b * 128 + j] = tanhf(acc + bias[j]);
    }
}

// =====================================================================
// fc2: (32,128) @ (16,128)^T + b -> tanh. One wave per output.
// =====================================================================
__global__ __launch_bounds__(256) void fc2_kernel(const float* __restrict__ h,
                                                  const float* __restrict__ w,
                                                  const float* __restrict__ bias,
                                                  float* __restrict__ out)
{
    int lane = threadIdx.x & 63;
    int o = blockIdx.x * 4 + (threadIdx.x >> 6);  // 0..511
    int b = o >> 4, j = o & 15;
    const float* hb = h + (size_t)b * 128;
    const float* wj = w + (size_t)j * 128;
    float acc = hb[lane] * wj[lane] + hb[lane + 64] * wj[lane + 64];
    for (int off = 32; off; off >>= 1) acc += __shfl_down(acc, off, 64);
    if (lane == 0) out[o] = tanhf(acc + bias[j]);
}

extern "C" void kernel_launch(void* const* d_in, const int* in_sizes, int n_in,
                              void* d_out, int out_size, void* d_ws, size_t ws_size,
                              hipStream_t stream)
{
    const float* x = (const float*)d_in[0];
    const int* orderings = (const int*)d_in[1];
    const float* sp_w = (const float*)d_in[2];
    const float* sp_b = (const float*)d_in[3];
    const float* conv_w[5];
    const float* conv_b[5];
    for (int j = 0; j < 5; ++j) {
        conv_w[j] = (const float*)d_in[4 + 2 * j];
        conv_b[j] = (const float*)d_in[5 + 2 * j];
    }
    const float* fc1_w = (const float*)d_in[14];
    const float* fc1_b = (const float*)d_in[15];
    const float* fc2_w = (const float*)d_in[16];
    const float* fc2_b = (const float*)d_in[17];

    float* ws = (float*)d_ws;

    // xt at [0, 4,194,304)
    transpose_kernel<<<NPTS / 64, 256, 0, stream>>>(x, ws);

    if (ws_size >= 12583936ull * 4ull) {
        // ---------- big path: merged B=64 ----------
        // floats: s [4,195,328, 12,583,936) ; c0 [0, 4,195,328) over dead xt ;
        //         c1 [4,195,328, 6,294,528) over dead s ; c3/feats/h1 after.
        size_t o_s = 4195328, o_c0 = 0, o_c1 = 4195328;
        size_t o_c3 = 6294528, o_f = 6560768, o_h1 = 6627328;

        smooth_kernel<<<512, 256, 0, stream>>>(ws, orderings, sp_w, sp_b, ws + o_s);
        smooth_kernel<<<512, 256, 0, stream>>>(ws, orderings + NPTS, sp_w, sp_b,
                                               ws + o_s + 4194304);

        conv_lds<2, 4, 2, 65536, 16388, 65536, 16385>
            <<<64 * 33, 256, 0, stream>>>(ws + o_s, conv_w[0], conv_b[0], ws + o_c0);
        conv_lds<4, 8, 2, 16388, 4100, 16385, 4097>
            <<<64 * 9, 256, 0, stream>>>(ws + o_c0, conv_w[1], conv_b[1], ws + o_c1);
        conv23_kernel<<<64 * 4, 256, 0, stream>>>(ws + o_c1, conv_w[2], conv_b[2],
                                                  conv_w[3], conv_b[3], ws + o_c3);
        conv4_kernel<<<64, 256, 0, stream>>>(ws + o_c3, conv_w[4], conv_b[4],
                                             ws + o_f, 0);
        fc1_kernel<<<256, 256, 0, stream>>>(ws + o_f, fc1_w, fc1_b, ws + o_h1);
        fc2_kernel<<<128, 256, 0, stream>>>(ws + o_h1, fc2_w, fc2_b, (float*)d_out);
    } else {
        // ---------- small path: per-SFC loop, B=32 (46.9 MB) ----------
        size_t o_s = 4194304, o_c0 = 8388608, o_c1 = 10486272;
        size_t o_c3 = 11535872, o_f = 11668992, o_h1 = 11735552;

        for (int i = 0; i < 2; ++i) {
            smooth_kernel<<<512, 256, 0, stream>>>(ws, orderings + (size_t)i * NPTS,
                                                   sp_w, sp_b, ws + o_s);
            conv_lds<2, 4, 2, 65536, 16388, 65536, 16385>
                <<<32 * 33, 256, 0, stream>>>(ws + o_s, conv_w[0], conv_b[0], ws + o_c0);
            conv_lds<4, 8, 2, 16388, 4100, 16385, 4097>
                <<<32 * 9, 256, 0, stream>>>(ws + o_c0, conv_w[1], conv_b[1], ws + o_c1);
            conv23_kernel<<<32 * 4, 256, 0, stream>>>(ws + o_c1, conv_w[2], conv_b[2],
                                                      conv_w[3], conv_b[3], ws + o_c3);
            conv4_kernel<<<32, 256, 0, stream>>>(ws + o_c3, conv_w[4], conv_b[4],
                                                 ws + o_f, i);
        }
        fc1_kernel<<<256, 256, 0, stream>>>(ws + o_f, fc1_w, fc1_b, ws + o_h1);
        fc2_kernel<<<128, 256, 0, stream>>>(ws + o_h1, fc2_w, fc2_b, (float*)d_out);
    }
}

// Round 9
// 197.914 us; speedup vs baseline: 7.0172x; 1.1364x over previous
//
#include <hip/hip_runtime.h>
#include <math.h>

#define NPTS 65536

__device__ __forceinline__ float4 ld4_guard(const float* __restrict__ row, int pos, int hi) {
    float4 v;
    if (pos >= 0 && pos + 4 <= hi) {
        v = *(const float4*)(row + pos);
    } else {
        v.x = (pos + 0 >= 0 && pos + 0 < hi) ? row[pos + 0] : 0.f;
        v.y = (pos + 1 >= 0 && pos + 1 < hi) ? row[pos + 1] : 0.f;
        v.z = (pos + 2 >= 0 && pos + 2 < hi) ? row[pos + 2] : 0.f;
        v.w = (pos + 3 >= 0 && pos + 3 < hi) ? row[pos + 3] : 0.f;
    }
    return v;
}

// =====================================================================
// transpose x (B,N,2) -> x_t (N, 64)  [x_t[n][b*2+c] = x[b][n][c]]
// =====================================================================
__global__ __launch_bounds__(256) void transpose_kernel(const float* __restrict__ x,
                                                        float* __restrict__ xt)
{
    __shared__ float tile[64][65];
    int n0 = blockIdx.x * 64;
    int tid = threadIdx.x;
    int lane = tid & 63, w = tid >> 6;
    const float2* x2 = (const float2*)x;
#pragma unroll
    for (int bq = 0; bq < 8; ++bq) {
        int b = bq * 4 + w;
        float2 v = x2[(size_t)b * NPTS + n0 + lane];
        tile[lane][b * 2 + 0] = v.x;
        tile[lane][b * 2 + 1] = v.y;
    }
    __syncthreads();
    int f4 = tid & 15;
#pragma unroll
    for (int rq = 0; rq < 4; ++rq) {
        int r = rq * 16 + (tid >> 4);
        float4 v = make_float4(tile[r][f4 * 4 + 0], tile[r][f4 * 4 + 1],
                               tile[r][f4 * 4 + 2], tile[r][f4 * 4 + 3]);
        *(float4*)&xt[(size_t)(n0 + r) * 64 + f4 * 4] = v;
    }
}

// =====================================================================
// smooth (one SFC): s[(b*2+c)*N + n] = tanh(sum_k xt[ord[clip(n-1+k)]][b*2+c]*sp_w[n,k]+sp_b[n])
// =====================================================================
__global__ __launch_bounds__(256) void smooth_kernel(const float* __restrict__ xt,
                                                     const int* __restrict__ ord,
                                                     const float* __restrict__ sp_w,
                                                     const float* __restrict__ sp_b,
                                                     float* __restrict__ s)
{
    __shared__ int s_idx[130];
    __shared__ float rows[130][65];
    int n0 = blockIdx.x * 128;
    int tid = threadIdx.x;
    if (tid < 130) {
        int g = n0 - 1 + tid;
        g = g < 0 ? 0 : (g > NPTS - 1 ? NPTS - 1 : g);
        s_idx[tid] = ord[g];
    }
    __syncthreads();
    for (int q = tid; q < 130 * 16; q += 256) {
        int r = q >> 4, f4 = q & 15;
        float4 v = *(const float4*)&xt[(size_t)s_idx[r] * 64 + f4 * 4];
        rows[r][f4 * 4 + 0] = v.x; rows[r][f4 * 4 + 1] = v.y;
        rows[r][f4 * 4 + 2] = v.z; rows[r][f4 * 4 + 3] = v.w;
    }
    __syncthreads();
    int n_local = tid & 127, half = tid >> 7;
    int n = n0 + n_local;
    float w0 = sp_w[n * 3 + 0], w1 = sp_w[n * 3 + 1], w2 = sp_w[n * 3 + 2];
    float bb = sp_b[n];
#pragma unroll 4
    for (int bc = 0; bc < 64; bc += 2) {
        int bce = bc + half;
        float v = w0 * rows[n_local][bce] + w1 * rows[n_local + 1][bce]
                + w2 * rows[n_local + 2][bce] + bb;
        s[(size_t)bce * NPTS + n] = tanhf(v);
    }
}

// =====================================================================
// LDS-staged conv (conv0 / conv1): float4 staging, LPT=2 sliding outputs,
// all COUT channels per thread, weights in LDS (broadcast reads).
// =====================================================================
template <int CIN, int COUT, int LPT, int ISTR, int OSTR, int LIN, int LOUT>
__global__ __launch_bounds__(256, 2) void conv_lds(
    const float* __restrict__ in,      // (B, CIN, ISTR)
    const float* __restrict__ w,       // (COUT, CIN, 32)
    const float* __restrict__ bias,
    float* __restrict__ out)           // (B, COUT, OSTR)
{
    constexpr int LTILE = 256 * LPT;
    constexpr int SPAN = 4 * LTILE + 28;     // divisible by 4
    constexpr int NF4 = SPAN / 4;
    constexpr int NT = (LOUT + LTILE - 1) / LTILE;
    constexpr int NV = 8 + LPT - 1;

    __shared__ float in_s[CIN][SPAN];
    __shared__ float w_s[COUT][CIN][32];

    int bid = blockIdx.x;
    int tile = bid % NT;
    int b = bid / NT;
    int tid = threadIdx.x;

    for (int i = tid; i < COUT * CIN * 32; i += 256)
        ((float*)w_s)[i] = w[i];

    int base = tile * LTILE * 4 - 16;
    const float* inb = in + (size_t)b * CIN * ISTR;
    if (base >= 0 && base + SPAN <= LIN) {
        for (int q = tid; q < CIN * NF4; q += 256) {
            int ci = q / NF4, p = q - ci * NF4;
            *(float4*)&in_s[ci][4 * p] =
                *(const float4*)(inb + (size_t)ci * ISTR + base + 4 * p);
        }
    } else {
        for (int q = tid; q < CIN * SPAN; q += 256) {
            int ci = q / SPAN, p = q - ci * SPAN;
            int pos = base + p;
            in_s[ci][p] = (pos >= 0 && pos < LIN) ? inb[(size_t)ci * ISTR + pos] : 0.f;
        }
    }
    __syncthreads();

    int lofs = tid * LPT;
    float acc[COUT][LPT];
#pragma unroll
    for (int c = 0; c < COUT; ++c) {
        float bv = bias[c];
#pragma unroll
        for (int j = 0; j < LPT; ++j) acc[c][j] = bv;
    }

#pragma unroll 1
    for (int ci = 0; ci < CIN; ++ci) {
        float4 v[NV];
#pragma unroll
        for (int k = 0; k < NV; ++k)
            v[k] = *(const float4*)&in_s[ci][4 * lofs + 4 * k];
#pragma unroll
        for (int k4 = 0; k4 < 8; ++k4) {
#pragma unroll
            for (int c = 0; c < COUT; ++c) {
                const float* wk = &w_s[c][ci][4 * k4];
                float wx = wk[0], wy = wk[1], wz = wk[2], ww = wk[3];
#pragma unroll
                for (int j = 0; j < LPT; ++j)
                    acc[c][j] += v[k4 + j].x * wx + v[k4 + j].y * wy
                               + v[k4 + j].z * wz + v[k4 + j].w * ww;
            }
        }
    }

    int l0 = tile * LTILE + lofs;
#pragma unroll
    for (int c = 0; c < COUT; ++c) {
        size_t row = ((size_t)b * COUT + c) * OSTR;
        if (l0 + 1 < LOUT) {
            float2 st2 = make_float2(tanhf(acc[c][0]), tanhf(acc[c][1]));
            *(float2*)&out[row + l0] = st2;
        } else if (l0 < LOUT) {
            out[row + l0] = tanhf(acc[c][0]);
        }
    }
}

// =====================================================================
// Fused conv2+conv3, occupancy-friendly: block = (b, t in [0,8)),
// t covers 33 l3 outputs. LDS ~49KB (st + c2s + w2 only); w3 read from
// global (wave-mostly-uniform, L1-hot). Rows padded to break bank aliasing.
// =====================================================================
__global__ void conv23_kernel(
    const float* __restrict__ c1,      // (B, 8, 4100), valid 4097
    const float* __restrict__ w2, const float* __restrict__ b2,
    const float* __restrict__ w3, const float* __restrict__ b3,
    float* __restrict__ c3out)         // (B, 16, 260), valid l3 < 257
{
    __shared__ float st[8][676];       // c1 window (668 used), stride%32=4
    __shared__ float c2s[16][168];     // c2 window (160 used), stride%32=8
    __shared__ float w2s[16][8][32];

    int b = blockIdx.x >> 3;
    int t = blockIdx.x & 7;
    int tid = threadIdx.x;

    for (int i = tid; i < 16 * 8 * 32; i += 256) ((float*)w2s)[i] = w2[i];

    int l3_0 = t * 33;                 // first l3 of this tile
    int s2 = 4 * l3_0 - 16;            // first c2 position needed
    int s1 = 4 * s2 - 16;              // first c1 position needed

    const float* c1b = c1 + (size_t)b * 8 * 4100;
    for (int q = tid; q < 8 * 167; q += 256) {   // 167 float4 = 668 floats
        int ci = q / 167, p = q - ci * 167;
        float4 v = ld4_guard(c1b + (size_t)ci * 4100, s1 + 4 * p, 4097);
        *(float4*)&st[ci][4 * p] = v;
    }
    __syncthreads();

    // ---- conv2: 160 positions, all 16 channels per thread ----
    if (tid < 160) {
        int i = tid;
        int l2 = s2 + i;
        bool valid = (l2 >= 0) && (l2 < 1025);
        float acc[16];
#pragma unroll
        for (int c = 0; c < 16; ++c) acc[c] = b2[c];
#pragma unroll 1
        for (int ci = 0; ci < 8; ++ci) {
            float4 v[8];
#pragma unroll
            for (int k = 0; k < 8; ++k)
                v[k] = *(const float4*)&st[ci][4 * i + 4 * k];
#pragma unroll
            for (int k4 = 0; k4 < 8; ++k4) {
#pragma unroll
                for (int c = 0; c < 16; ++c) {
                    const float* wk = &w2s[c][ci][4 * k4];
                    acc[c] += v[k4].x * wk[0] + v[k4].y * wk[1]
                            + v[k4].z * wk[2] + v[k4].w * wk[3];
                }
            }
        }
#pragma unroll
        for (int c = 0; c < 16; ++c) c2s[c][i] = valid ? tanhf(acc[c]) : 0.f;
    }
    __syncthreads();

    // ---- conv3: 16 co x 33 l3 outputs; weights from global (L1-hot) ----
    for (int q = tid; q < 16 * 33; q += 256) {
        int co = q / 33, j = q - co * 33;
        int l3 = l3_0 + j;
        if (l3 < 257) {
            float acc = b3[co];
            const float* w3c = w3 + (size_t)co * 16 * 32;
#pragma unroll 1
            for (int ci = 0; ci < 16; ++ci) {
#pragma unroll
                for (int k4 = 0; k4 < 8; ++k4) {
                    float4 v = *(const float4*)&c2s[ci][4 * j + 4 * k4];
                    float4 wv = *(const float4*)(w3c + ci * 32 + 4 * k4);
                    acc += v.x * wv.x + v.y * wv.y + v.z * wv.z + v.w * wv.w;
                }
            }
            c3out[((size_t)b * 16 + co) * 260 + l3] = tanhf(acc);
        }
    }
}

// =====================================================================
// conv4 + concat into feats. One block per b.
// =====================================================================
__global__ __launch_bounds__(256) void conv4_kernel(
    const float* __restrict__ c3,      // (B, 16, 260), valid l3 < 257
    const float* __restrict__ w4, const float* __restrict__ b4,
    float* __restrict__ feats, int ibase)
{
    __shared__ float st[16][292];
    __shared__ float w4s[16][16][32];
    int b = blockIdx.x, tid = threadIdx.x;
    for (int i = tid; i < 16 * 16 * 32; i += 256) ((float*)w4s)[i] = w4[i];
    const float* c3b = c3 + (size_t)b * 16 * 260;
    for (int q = tid; q < 16 * 72; q += 256) {
        int ci = q / 72, p = q - ci * 72;
        float4 v = ld4_guard(c3b + (size_t)ci * 260, 4 * p - 16, 257);
        *(float4*)&st[ci][4 * p] = v;
    }
    __syncthreads();
    for (int q = tid; q < 1040; q += 256) {
        int co = q / 65, l4 = q - co * 65;
        float acc = b4[co];
#pragma unroll 1
        for (int ci = 0; ci < 16; ++ci) {
#pragma unroll
            for (int k4 = 0; k4 < 8; ++k4) {
                float4 v = *(const float4*)&st[ci][4 * l4 + 4 * k4];
                const float* wk = &w4s[co][ci][4 * k4];
                acc += v.x * wk[0] + v.y * wk[1] + v.z * wk[2] + v.w * wk[3];
            }
        }
        feats[(size_t)(b & 31) * 2080 + (size_t)((b >> 5) + ibase) * 1040 + co * 65 + l4]
            = tanhf(acc);
    }
}

// =====================================================================
// fc1: (32,2080) @ (128,2080)^T + b -> tanh. Wave per output, float4 dots.
// =====================================================================
__global__ __launch_bounds__(256) void fc1_kernel(const float* __restrict__ h,
                                                  const float* __restrict__ w,
                                                  const float* __restrict__ bias,
                                                  float* __restrict__ out)
{
    int lane = threadIdx.x & 63;
    int wid = blockIdx.x * 4 + (threadIdx.x >> 6);  // 0..1023
#pragma unroll
    for (int r = 0; r < 4; ++r) {
        int o = wid + r * 1024;
        int b = o >> 7, j = o & 127;
        const float4* h4 = (const float4*)(h + (size_t)b * 2080);
        const float4* w4 = (const float4*)(w + (size_t)j * 2080);
        float acc = 0.f;
#pragma unroll
        for (int q = 0; q < 8; ++q) {
            float4 a = h4[lane + 64 * q], c = w4[lane + 64 * q];
            acc += a.x * c.x + a.y * c.y + a.z * c.z + a.w * c.w;
        }
        if (lane < 8) {
            float4 a = h4[512 + lane], c = w4[512 + lane];
            acc += a.x * c.x + a.y * c.y + a.z * c.z + a.w * c.w;
        }
        for (int off = 32; off; off >>= 1) acc += __shfl_down(acc, off, 64);
        if (lane == 0) out[b * 128 + j] = tanhf(acc + bias[j]);
    }
}

// =====================================================================
// fc2: (32,128) @ (16,128)^T + b -> tanh. One wave per output.
// =====================================================================
__global__ __launch_bounds__(256) void fc2_kernel(const float* __restrict__ h,
                                                  const float* __restrict__ w,
                                                  const float* __restrict__ bias,
                                                  float* __restrict__ out)
{
    int lane = threadIdx.x & 63;
    int o = blockIdx.x * 4 + (threadIdx.x >> 6);  // 0..511
    int b = o >> 4, j = o & 15;
    const float* hb = h + (size_t)b * 128;
    const float* wj = w + (size_t)j * 128;
    float acc = hb[lane] * wj[lane] + hb[lane + 64] * wj[lane + 64];
    for (int off = 32; off; off >>= 1) acc += __shfl_down(acc, off, 64);
    if (lane == 0) out[o] = tanhf(acc + bias[j]);
}

extern "C" void kernel_launch(void* const* d_in, const int* in_sizes, int n_in,
                              void* d_out, int out_size, void* d_ws, size_t ws_size,
                              hipStream_t stream)
{
    const float* x = (const float*)d_in[0];
    const int* orderings = (const int*)d_in[1];
    const float* sp_w = (const float*)d_in[2];
    const float* sp_b = (const float*)d_in[3];
    const float* conv_w[5];
    const float* conv_b[5];
    for (int j = 0; j < 5; ++j) {
        conv_w[j] = (const float*)d_in[4 + 2 * j];
        conv_b[j] = (const float*)d_in[5 + 2 * j];
    }
    const float* fc1_w = (const float*)d_in[14];
    const float* fc1_b = (const float*)d_in[15];
    const float* fc2_w = (const float*)d_in[16];
    const float* fc2_b = (const float*)d_in[17];

    float* ws = (float*)d_ws;

    // xt at [0, 4,194,304)
    transpose_kernel<<<NPTS / 64, 256, 0, stream>>>(x, ws);

    if (ws_size >= 12583936ull * 4ull) {
        // ---------- big path: merged B=64 ----------
        // floats: s [4,195,328, 12,583,936) ; c0 [0, 4,195,328) over dead xt ;
        //         c1 [4,195,328, 6,294,528) over dead s ; c3/feats/h1 after.
        size_t o_s = 4195328, o_c0 = 0, o_c1 = 4195328;
        size_t o_c3 = 6294528, o_f = 6560768, o_h1 = 6627328;

        smooth_kernel<<<512, 256, 0, stream>>>(ws, orderings, sp_w, sp_b, ws + o_s);
        smooth_kernel<<<512, 256, 0, stream>>>(ws, orderings + NPTS, sp_w, sp_b,
                                               ws + o_s + 4194304);

        conv_lds<2, 4, 2, 65536, 16388, 65536, 16385>
            <<<64 * 33, 256, 0, stream>>>(ws + o_s, conv_w[0], conv_b[0], ws + o_c0);
        conv_lds<4, 8, 2, 16388, 4100, 16385, 4097>
            <<<64 * 9, 256, 0, stream>>>(ws + o_c0, conv_w[1], conv_b[1], ws + o_c1);
        conv23_kernel<<<64 * 8, 256, 0, stream>>>(ws + o_c1, conv_w[2], conv_b[2],
                                                  conv_w[3], conv_b[3], ws + o_c3);
        conv4_kernel<<<64, 256, 0, stream>>>(ws + o_c3, conv_w[4], conv_b[4],
                                             ws + o_f, 0);
        fc1_kernel<<<256, 256, 0, stream>>>(ws + o_f, fc1_w, fc1_b, ws + o_h1);
        fc2_kernel<<<128, 256, 0, stream>>>(ws + o_h1, fc2_w, fc2_b, (float*)d_out);
    } else {
        // ---------- small path: per-SFC loop, B=32 (46.9 MB) ----------
        size_t o_s = 4194304, o_c0 = 8388608, o_c1 = 10486272;
        size_t o_c3 = 11535872, o_f = 11668992, o_h1 = 11735552;

        for (int i = 0; i < 2; ++i) {
            smooth_kernel<<<512, 256, 0, stream>>>(ws, orderings + (size_t)i * NPTS,
                                                   sp_w, sp_b, ws + o_s);
            conv_lds<2, 4, 2, 65536, 16388, 65536, 16385>
                <<<32 * 33, 256, 0, stream>>>(ws + o_s, conv_w[0], conv_b[0], ws + o_c0);
            conv_lds<4, 8, 2, 16388, 4100, 16385, 4097>
                <<<32 * 9, 256, 0, stream>>>(ws + o_c0, conv_w[1], conv_b[1], ws + o_c1);
            conv23_kernel<<<32 * 8, 256, 0, stream>>>(ws + o_c1, conv_w[2], conv_b[2],
                                                      conv_w[3], conv_b[3], ws + o_c3);
            conv4_kernel<<<32, 256, 0, stream>>>(ws + o_c3, conv_w[4], conv_b[4],
                                                 ws + o_f, i);
        }
        fc1_kernel<<<256, 256, 0, stream>>>(ws + o_f, fc1_w, fc1_b, ws + o_h1);
        fc2_kernel<<<128, 256, 0, stream>>>(ws + o_h1, fc2_w, fc2_b, (float*)d_out);
    }
}